// Round 3
// baseline (3219.324 us; speedup 1.0000x reference)
//
#include <hip/hip_runtime.h>
#include <hip/hip_bf16.h>

// RITS recurrent imputation, B=1024 T=100 F=64 H=256.
// Round 3: latency-bound -> bandwidth-bound weight streaming.
//  - P5 (gates GEMM) B-fragments: 3-deep software-pipelined global->VGPR
//    prefetch (12 k-slots x 4 gates), ~128KB+/CU in flight.
//  - h,c state in registers (wave-column ownership identical in P1/P5).
//  - Wdh frags, biases, wdx diag preloaded once; Whist/Wfeatm/Wcomb batched
//    prefetch at P2 entry; inputs prefetched one step ahead.
//  - tanh via __expf (2/(1+e^-2x)-1).

#define Bz 1024
#define Tz 100
#define Fz 64
#define Hz 256
#define GRID 64
#define RPB 16

typedef __attribute__((ext_vector_type(8))) short short8;
typedef __attribute__((ext_vector_type(4))) float floatx4;
typedef __hip_bfloat16 bf16;

#define MFMA16(a, b, c) __builtin_amdgcn_mfma_f32_16x16x32_bf16((a), (b), (c), 0, 0, 0)

__device__ __forceinline__ float sigmf(float x) { return 1.0f / (1.0f + __expf(-x)); }
__device__ __forceinline__ float tanhfast(float x) { return 2.0f / (1.0f + __expf(-2.0f * x)) - 1.0f; }

// ws bf16 layout (elements):
// Wdh[256x64]@0, Whist[64x256]@16384, Wfeatm[64x64]@32768, Wcomb[64x128]@36864,
// Wih[1024x128]@45056, Whh[1024x256]@176128 ; total 438272 bf16.
// then f32: wdx_diag[64], lossbuf[64*100*4].

__global__ void rits_convert(const float* __restrict__ Wdh, const float* __restrict__ Wdx,
                             const float* __restrict__ Whist, const float* __restrict__ Wfeat,
                             const float* __restrict__ Wcomb, const float* __restrict__ Wih,
                             const float* __restrict__ Whh, bf16* __restrict__ wsbf,
                             float* __restrict__ wdxd) {
    int idx = blockIdx.x * blockDim.x + threadIdx.x;
    if (idx < 64) wdxd[idx] = Wdx[idx * 65];  // diag of W_dx
    if (idx >= 438272) return;
    float v;
    if (idx < 16384) v = Wdh[idx];
    else if (idx < 32768) v = Whist[idx - 16384];
    else if (idx < 36864) { int i = idx - 32768; v = ((i >> 6) == (i & 63)) ? 0.0f : Wfeat[i]; }
    else if (idx < 45056) v = Wcomb[idx - 36864];
    else if (idx < 176128) v = Wih[idx - 45056];
    else v = Whh[idx - 176128];
    wsbf[idx] = __float2bfloat16(v);
}

__global__ __launch_bounds__(1024, 4) void rits_main(
    const float* __restrict__ X, const float* __restrict__ Mm, const float* __restrict__ Dd,
    const float* __restrict__ b_dh, const float* __restrict__ b_dx,
    const float* __restrict__ b_hist, const float* __restrict__ b_feat,
    const float* __restrict__ b_comb, const float* __restrict__ b_ih,
    const float* __restrict__ b_hh,
    const bf16* __restrict__ Wdh, const bf16* __restrict__ Whist,
    const bf16* __restrict__ Wfeatm, const bf16* __restrict__ Wcomb,
    const bf16* __restrict__ Wih, const bf16* __restrict__ Whh,
    const float* __restrict__ wdxd, float* __restrict__ lossbuf, float* __restrict__ out) {
    // ---- LDS (~30 KB) ----
    __shared__ __align__(16) bf16 sh_hbf[RPB * 264];   // decayed h, bf16 A-operand
    __shared__ __align__(16) float sh_x[RPB * 64];
    __shared__ __align__(16) float sh_m[RPB * 64];
    __shared__ __align__(16) bf16 sh_dbf[RPB * 72];    // d bf16
    __shared__ __align__(16) bf16 sh_xcbf[RPB * 72];   // x_c bf16
    __shared__ __align__(16) bf16 sh_gmbf[RPB * 136];  // [gamma_x | m] bf16
    __shared__ __align__(16) bf16 sh_inbf[RPB * 136];  // [c_c | m] bf16
    __shared__ float sh_lred[16];
    __shared__ float sh_msum[16];

    const int tid = threadIdx.x;
    const int lane = tid & 63;
    const int wid = tid >> 6;   // wave id 0..15
    const int l16 = lane & 15;
    const int q = lane >> 4;    // quad 0..3
    const int b0 = blockIdx.x * RPB;
    const int colH = wid * 16 + l16;  // owned H column (P1/P5); = F col for waves 0-3

    // persistent per-thread LSTM state: rows q*4+r, col colH
    float hreg[4] = {0.f, 0.f, 0.f, 0.f};
    float creg[4] = {0.f, 0.f, 0.f, 0.f};

    // ---- step-invariant preloads ----
    const short8 wdh0 = *(const short8*)(Wdh + colH * 64 + q * 8);
    const short8 wdh1 = *(const short8*)(Wdh + colH * 64 + 32 + q * 8);
    const float bd = b_dh[colH];
    const float bi = b_ih[colH] + b_hh[colH];
    const float bff = b_ih[256 + colH] + b_hh[256 + colH];
    const float bgg = b_ih[512 + colH] + b_hh[512 + colH];
    const float boo = b_ih[768 + colH] + b_hh[768 + colH];
    const float wdxf = wdxd[lane];
    const float bdxf = b_dx[lane];
    float bh = 0.f, bft = 0.f, bc = 0.f;
    if (wid < 4) { bh = b_hist[colH]; bft = b_feat[colH]; bc = b_comb[colH]; }

    // input prefetch (row = wid, f = lane), one step ahead
    const size_t g0 = (size_t)(b0 + wid) * Tz * Fz + lane;
    float xv = X[g0], mv = Mm[g0], dv = Dd[g0];

    for (int t = 0; t < Tz; ++t) {
        // ---- P0: stage x,m,d tile; gamma_x; m halves; mask-sum ----
        {
            const int row = wid, f = lane;
            sh_x[row * 64 + f] = xv;
            sh_m[row * 64 + f] = mv;
            float gx = __expf(-fmaxf(dv * wdxf + bdxf, 0.0f));
            sh_gmbf[row * 136 + f] = __float2bfloat16(gx);
            bf16 mb = __float2bfloat16(mv);
            sh_gmbf[row * 136 + 64 + f] = mb;
            sh_inbf[row * 136 + 64 + f] = mb;
            sh_dbf[row * 72 + f] = __float2bfloat16(dv);
            float v0 = mv;
#pragma unroll
            for (int off = 32; off; off >>= 1) v0 += __shfl_xor(v0, off, 64);
            if (lane == 0) sh_msum[wid] = v0;
        }
        __syncthreads();  // bar A

        // ---- P1: gamma_h; h *= gamma_h (registers); publish bf16 h ----
        {
            short8 a0 = *(const short8*)(sh_dbf + l16 * 72 + q * 8);
            short8 a1 = *(const short8*)(sh_dbf + l16 * 72 + 32 + q * 8);
            floatx4 acc = {0.f, 0.f, 0.f, 0.f};
            acc = MFMA16(a0, wdh0, acc);
            acc = MFMA16(a1, wdh1, acc);
#pragma unroll
            for (int r = 0; r < 4; ++r) {
                float g = __expf(-fmaxf(acc[r] + bd, 0.0f));
                hreg[r] *= g;
                sh_hbf[(q * 4 + r) * 264 + colH] = __float2bfloat16(hreg[r]);
            }
        }
        __syncthreads();  // bar B

        // ---- P2: x_h (waves 0-3); batched prefetch of P2+P34 weights ----
        float xh[4];
        float l1 = 0.f, l2 = 0.f, l3 = 0.f;
        short8 wf0, wf1, wc0, wc1, wc2, wc3;
        if (wid < 4) {
            short8 wh[8];
#pragma unroll
            for (int kb = 0; kb < 8; ++kb)
                wh[kb] = *(const short8*)(Whist + colH * 256 + kb * 32 + q * 8);
            wf0 = *(const short8*)(Wfeatm + colH * 64 + q * 8);
            wf1 = *(const short8*)(Wfeatm + colH * 64 + 32 + q * 8);
            wc0 = *(const short8*)(Wcomb + colH * 128 + q * 8);
            wc1 = *(const short8*)(Wcomb + colH * 128 + 32 + q * 8);
            wc2 = *(const short8*)(Wcomb + colH * 128 + 64 + q * 8);
            wc3 = *(const short8*)(Wcomb + colH * 128 + 96 + q * 8);
            floatx4 acc = {0.f, 0.f, 0.f, 0.f};
#pragma unroll
            for (int kb = 0; kb < 8; ++kb) {
                short8 a = *(const short8*)(sh_hbf + l16 * 264 + kb * 32 + q * 8);
                acc = MFMA16(a, wh[kb], acc);
            }
#pragma unroll
            for (int r = 0; r < 4; ++r) {
                int row = q * 4 + r;
                xh[r] = acc[r] + bh;
                float xx = sh_x[row * 64 + colH], mm = sh_m[row * 64 + colH];
                l1 += fabsf(xh[r] - xx) * mm;
                float xc = mm * xx + (1.0f - mm) * xh[r];
                sh_xcbf[row * 72 + colH] = __float2bfloat16(xc);
            }
        }
        __syncthreads();  // bar C

        // ---- P34: z_h, alpha, c_h, imputed write, c_c (waves 0-3) ----
        if (wid < 4) {
            floatx4 accz = {0.f, 0.f, 0.f, 0.f};
            {
                short8 a = *(const short8*)(sh_xcbf + l16 * 72 + q * 8);
                accz = MFMA16(a, wf0, accz);
                a = *(const short8*)(sh_xcbf + l16 * 72 + 32 + q * 8);
                accz = MFMA16(a, wf1, accz);
            }
            floatx4 acca = {0.f, 0.f, 0.f, 0.f};
            {
                short8 a = *(const short8*)(sh_gmbf + l16 * 136 + q * 8);
                acca = MFMA16(a, wc0, acca);
                a = *(const short8*)(sh_gmbf + l16 * 136 + 32 + q * 8);
                acca = MFMA16(a, wc1, acca);
                a = *(const short8*)(sh_gmbf + l16 * 136 + 64 + q * 8);
                acca = MFMA16(a, wc2, acca);
                a = *(const short8*)(sh_gmbf + l16 * 136 + 96 + q * 8);
                acca = MFMA16(a, wc3, acca);
            }
#pragma unroll
            for (int r = 0; r < 4; ++r) {
                int row = q * 4 + r;
                float xx = sh_x[row * 64 + colH], mm = sh_m[row * 64 + colH];
                float z = accz[r] + bft;
                l2 += fabsf(z - xx) * mm;
                float al = sigmf(acca[r] + bc);
                float ch = al * z + (1.0f - al) * xh[r];
                l3 += fabsf(ch - xx) * mm;
                float imp = mm * xx + (1.0f - mm) * ch;  // == c_c
                out[((size_t)(b0 + row) * Tz + t) * Fz + colH] = imp;
                sh_inbf[row * 136 + colH] = __float2bfloat16(imp);
            }
            float v1 = l1, v2 = l2, v3 = l3;
#pragma unroll
            for (int off = 32; off; off >>= 1) {
                v1 += __shfl_xor(v1, off, 64);
                v2 += __shfl_xor(v2, off, 64);
                v3 += __shfl_xor(v3, off, 64);
            }
            if (lane == 0) {
                sh_lred[wid * 4 + 0] = v1;
                sh_lred[wid * 4 + 1] = v2;
                sh_lred[wid * 4 + 2] = v3;
            }
        }
        __syncthreads();  // bar D

        if (tid == 0) {
            float s0 = 0.0f;
#pragma unroll
            for (int i = 0; i < 16; ++i) s0 += sh_msum[i];
            float* lb = lossbuf + ((size_t)blockIdx.x * Tz + t) * 4;
            lb[0] = s0;
            lb[1] = sh_lred[0] + sh_lred[4] + sh_lred[8] + sh_lred[12];
            lb[2] = sh_lred[1] + sh_lred[5] + sh_lred[9] + sh_lred[13];
            lb[3] = sh_lred[2] + sh_lred[6] + sh_lred[10] + sh_lred[14];
        }

        // input prefetch for t+1 (consumed at next P0)
        if (t + 1 < Tz) {
            size_t g = g0 + (size_t)(t + 1) * Fz;
            xv = X[g]; mv = Mm[g]; dv = Dd[g];
        }

        // ---- P5: gates GEMM, 3-deep pipelined B-frag stream.
        // 12 k-slots: s<4 -> Wih kb=s (A = sh_inbf); s>=4 -> Whh kb=s-4 (A = sh_hbf).
        {
            floatx4 acc[4];
#pragma unroll
            for (int g = 0; g < 4; ++g) acc[g] = (floatx4){0.f, 0.f, 0.f, 0.f};
            short8 bbuf[3][4];
#pragma unroll
            for (int s = 0; s < 3; ++s)
#pragma unroll
                for (int g = 0; g < 4; ++g)
                    bbuf[s][g] = *(const short8*)(Wih + (g * 256 + colH) * 128 + s * 32 + q * 8);
#pragma unroll
            for (int s = 0; s < 12; ++s) {
                short8 a = (s < 4) ? *(const short8*)(sh_inbf + l16 * 136 + s * 32 + q * 8)
                                   : *(const short8*)(sh_hbf + l16 * 264 + (s - 4) * 32 + q * 8);
#pragma unroll
                for (int g = 0; g < 4; ++g) acc[g] = MFMA16(a, bbuf[s % 3][g], acc[g]);
                if (s < 9) {
                    const int s3 = s + 3;
#pragma unroll
                    for (int g = 0; g < 4; ++g)
                        bbuf[s % 3][g] =
                            (s3 < 4) ? *(const short8*)(Wih + (g * 256 + colH) * 128 + s3 * 32 + q * 8)
                                     : *(const short8*)(Whh + (g * 256 + colH) * 256 + (s3 - 4) * 32 + q * 8);
                }
            }
#pragma unroll
            for (int r = 0; r < 4; ++r) {
                float ig = sigmf(acc[0][r] + bi);
                float fg = sigmf(acc[1][r] + bff);
                float gg = tanhfast(acc[2][r] + bgg);
                float og = sigmf(acc[3][r] + boo);
                creg[r] = fg * creg[r] + ig * gg;
                hreg[r] = og * tanhfast(creg[r]);
            }
        }
        __syncthreads();  // bar E (protects sh_* reuse by next step's P0/P5)
    }
}

__global__ void rits_finalize(const float* __restrict__ lossbuf, float* __restrict__ out) {
    __shared__ float m1[Tz], m2[Tz], m3[Tz];
    int t = threadIdx.x;
    if (t < Tz) {
        float s0 = 0.0f, s1 = 0.0f, s2 = 0.0f, s3 = 0.0f;
        for (int g = 0; g < GRID; ++g) {
            const float* lb = lossbuf + ((size_t)g * Tz + t) * 4;
            s0 += lb[0]; s1 += lb[1]; s2 += lb[2]; s3 += lb[3];
        }
        float inv = 1.0f / (s0 + 1e-9f);
        m1[t] = s1 * inv; m2[t] = s2 * inv; m3[t] = s3 * inv;
    }
    __syncthreads();
    if (t == 0) {
        float rm = 0.0f, rl = 0.0f;
        for (int i = 0; i < Tz; ++i) {  // literal replay of reference accumulation
            rl += m1[i]; rl += m2[i]; rm += m3[i]; rl += rm;
        }
        out[(size_t)Bz * Tz * Fz] = rm / (float)Tz;
        out[(size_t)Bz * Tz * Fz + 1] = rl / (3.0f * (float)Tz);
    }
}

extern "C" void kernel_launch(void* const* d_in, const int* in_sizes, int n_in,
                              void* d_out, int out_size, void* d_ws, size_t ws_size,
                              hipStream_t stream) {
    const float* X = (const float*)d_in[0];
    const float* Mm = (const float*)d_in[1];
    const float* Dd = (const float*)d_in[2];
    const float* Wdh = (const float*)d_in[3];
    const float* b_dh = (const float*)d_in[4];
    const float* Wdx = (const float*)d_in[5];
    const float* b_dx = (const float*)d_in[6];
    const float* Whist = (const float*)d_in[7];
    const float* b_hist = (const float*)d_in[8];
    const float* Wfeat = (const float*)d_in[9];
    const float* b_feat = (const float*)d_in[10];
    const float* Wcomb = (const float*)d_in[11];
    const float* b_comb = (const float*)d_in[12];
    const float* Wih = (const float*)d_in[13];
    const float* b_ih = (const float*)d_in[14];
    const float* Whh = (const float*)d_in[15];
    const float* b_hh = (const float*)d_in[16];
    float* out = (float*)d_out;

    bf16* wsbf = (bf16*)d_ws;
    float* wdxd = (float*)((char*)d_ws + (size_t)438272 * 2);
    float* lossbuf = wdxd + 64;

    rits_convert<<<1712, 256, 0, stream>>>(Wdh, Wdx, Whist, Wfeat, Wcomb, Wih, Whh, wsbf, wdxd);
    rits_main<<<GRID, 1024, 0, stream>>>(X, Mm, Dd, b_dh, b_dx, b_hist, b_feat, b_comb, b_ih, b_hh,
                                         wsbf + 0, wsbf + 16384, wsbf + 32768, wsbf + 36864,
                                         wsbf + 45056, wsbf + 176128, wdxd, lossbuf, out);
    rits_finalize<<<1, 128, 0, stream>>>(lossbuf, out);
}

// Round 4
// 2531.184 us; speedup vs baseline: 1.2719x; 1.2719x over previous
//
#include <hip/hip_runtime.h>
#include <hip/hip_bf16.h>

// RITS recurrent imputation, B=1024 T=100 F=64 H=256.
// Round 4: P5 weight stream via global_load_lds (width=16) double-buffered
// LDS pipeline; weights pre-reordered into slot-major consumption layout.
// Small GEMM weights (Whist/Wfeatm/Wcomb/Wdh) register-resident across T-loop.

#define Bz 1024
#define Tz 100
#define Fz 64
#define Hz 256
#define GRID 64
#define RPB 16

typedef __attribute__((ext_vector_type(8))) short short8;
typedef __attribute__((ext_vector_type(4))) float floatx4;
typedef __hip_bfloat16 bf16;

#define MFMA16(a, b, c) __builtin_amdgcn_mfma_f32_16x16x32_bf16((a), (b), (c), 0, 0, 0)

__device__ __forceinline__ float sigmf(float x) { return 1.0f / (1.0f + __expf(-x)); }
__device__ __forceinline__ float tanhfast(float x) { return 2.0f / (1.0f + __expf(-2.0f * x)) - 1.0f; }

// ws bf16 layout (elements):
// Wdh[256x64]@0, Whist[64x256]@16384, Wfeatm[64x64]@32768, Wcomb[64x128]@36864,
// Wp5[12*32768]@45056 (slot-major reorder of Wih/Whh); total 438272 bf16.
// then f32: wdx_diag[64], lossbuf[64*100*4].
// Wp5 flat index: s*32768 + w*2048 + g*512 + l*32 + q*8 + e, where
// output row n = g*256 + w*16 + l; s<4 -> Wih[n][s*32+q*8+e], s>=4 -> Whh[n][(s-4)*32+q*8+e].

__global__ void rits_convert(const float* __restrict__ Wdh, const float* __restrict__ Wdx,
                             const float* __restrict__ Whist, const float* __restrict__ Wfeat,
                             const float* __restrict__ Wcomb, const float* __restrict__ Wih,
                             const float* __restrict__ Whh, bf16* __restrict__ wsbf,
                             float* __restrict__ wdxd) {
    int idx = blockIdx.x * blockDim.x + threadIdx.x;
    if (idx < 64) wdxd[idx] = Wdx[idx * 65];  // diag of W_dx
    if (idx >= 438272) return;
    float v;
    if (idx < 16384) v = Wdh[idx];
    else if (idx < 32768) v = Whist[idx - 16384];
    else if (idx < 36864) { int i = idx - 32768; v = ((i >> 6) == (i & 63)) ? 0.0f : Wfeat[i]; }
    else if (idx < 45056) v = Wcomb[idx - 36864];
    else {
        int i = idx - 45056;
        int e = i & 7, q = (i >> 3) & 3, l = (i >> 5) & 15, g = (i >> 9) & 3, w = (i >> 11) & 15;
        int s = i >> 15;
        int n = g * 256 + w * 16 + l;
        v = (s < 4) ? Wih[n * 128 + s * 32 + q * 8 + e] : Whh[n * 256 + (s - 4) * 32 + q * 8 + e];
    }
    wsbf[idx] = __float2bfloat16(v);
}

// cooperative tid-linear DMA of one 64KB slot into LDS (identity layout)
__device__ __forceinline__ void stage_slot(const bf16* __restrict__ wp5, bf16* dst, int s,
                                           int tid) {
    const bf16* gsrc = wp5 + (size_t)s * 32768 + tid * 8;
    bf16* ldst = dst + tid * 8;
#pragma unroll
    for (int i = 0; i < 4; ++i) {
        __builtin_amdgcn_global_load_lds(
            (const __attribute__((address_space(1))) unsigned int*)(gsrc + i * 8192),
            (__attribute__((address_space(3))) unsigned int*)(ldst + i * 8192), 16, 0, 0);
    }
}

__global__ __launch_bounds__(1024, 4) void rits_main(
    const float* __restrict__ X, const float* __restrict__ Mm, const float* __restrict__ Dd,
    const float* __restrict__ b_dh, const float* __restrict__ b_dx,
    const float* __restrict__ b_hist, const float* __restrict__ b_feat,
    const float* __restrict__ b_comb, const float* __restrict__ b_ih,
    const float* __restrict__ b_hh,
    const bf16* __restrict__ Wdh, const bf16* __restrict__ Whist,
    const bf16* __restrict__ Wfeatm, const bf16* __restrict__ Wcomb,
    const bf16* __restrict__ Wp5,
    const float* __restrict__ wdxd, float* __restrict__ lossbuf, float* __restrict__ out) {
    // ---- LDS: 2x64KB weight stage + activations = 161,152 B (<160 KiB) ----
    __shared__ __align__(16) bf16 sh_wbuf[2][32768];
    __shared__ __align__(16) bf16 sh_hbf[RPB * 264];
    __shared__ __align__(16) float sh_x[RPB * 64];
    __shared__ __align__(16) float sh_m[RPB * 64];
    __shared__ __align__(16) bf16 sh_dbf[RPB * 72];
    __shared__ __align__(16) bf16 sh_xcbf[RPB * 72];
    __shared__ __align__(16) bf16 sh_gmbf[RPB * 136];
    __shared__ __align__(16) bf16 sh_inbf[RPB * 136];
    __shared__ float sh_lred[16];
    __shared__ float sh_msum[16];

    const int tid = threadIdx.x;
    const int lane = tid & 63;
    const int wid = tid >> 6;   // 0..15
    const int l16 = lane & 15;
    const int q = lane >> 4;    // 0..3
    const int b0 = blockIdx.x * RPB;
    const int colH = wid * 16 + l16;

    float hreg[4] = {0.f, 0.f, 0.f, 0.f};
    float creg[4] = {0.f, 0.f, 0.f, 0.f};

    // ---- step-invariant register preloads ----
    const short8 wdh0 = *(const short8*)(Wdh + colH * 64 + q * 8);
    const short8 wdh1 = *(const short8*)(Wdh + colH * 64 + 32 + q * 8);
    const float bd = b_dh[colH];
    const float bi = b_ih[colH] + b_hh[colH];
    const float bff = b_ih[256 + colH] + b_hh[256 + colH];
    const float bgg = b_ih[512 + colH] + b_hh[512 + colH];
    const float boo = b_ih[768 + colH] + b_hh[768 + colH];
    const float wdxf = wdxd[lane];
    const float bdxf = b_dx[lane];
    float bh = 0.f, bft = 0.f, bc = 0.f;
    short8 wh[8], wf0, wf1, wc0, wc1, wc2, wc3;
    if (wid < 4) {
        bh = b_hist[colH]; bft = b_feat[colH]; bc = b_comb[colH];
#pragma unroll
        for (int kb = 0; kb < 8; ++kb)
            wh[kb] = *(const short8*)(Whist + colH * 256 + kb * 32 + q * 8);
        wf0 = *(const short8*)(Wfeatm + colH * 64 + q * 8);
        wf1 = *(const short8*)(Wfeatm + colH * 64 + 32 + q * 8);
        wc0 = *(const short8*)(Wcomb + colH * 128 + q * 8);
        wc1 = *(const short8*)(Wcomb + colH * 128 + 32 + q * 8);
        wc2 = *(const short8*)(Wcomb + colH * 128 + 64 + q * 8);
        wc3 = *(const short8*)(Wcomb + colH * 128 + 96 + q * 8);
    }

    // input prefetch (row = wid, f = lane)
    const size_t g0 = (size_t)(b0 + wid) * Tz * Fz + lane;
    float xv = X[g0], mv = Mm[g0], dv = Dd[g0];

    for (int t = 0; t < Tz; ++t) {
        // ---- P0: stage inputs into LDS; gamma_x; m halves; mask-sum ----
        {
            const int row = wid, f = lane;
            sh_x[row * 64 + f] = xv;
            sh_m[row * 64 + f] = mv;
            float gx = __expf(-fmaxf(dv * wdxf + bdxf, 0.0f));
            sh_gmbf[row * 136 + f] = __float2bfloat16(gx);
            bf16 mb = __float2bfloat16(mv);
            sh_gmbf[row * 136 + 64 + f] = mb;
            sh_inbf[row * 136 + 64 + f] = mb;
            sh_dbf[row * 72 + f] = __float2bfloat16(dv);
            float v0 = mv;
#pragma unroll
            for (int off = 32; off; off >>= 1) v0 += __shfl_xor(v0, off, 64);
            if (lane == 0) sh_msum[wid] = v0;
        }
        __syncthreads();  // bar A

        // ---- P1: gamma_h; h *= gamma_h; publish bf16 h ----
        {
            short8 a0 = *(const short8*)(sh_dbf + l16 * 72 + q * 8);
            short8 a1 = *(const short8*)(sh_dbf + l16 * 72 + 32 + q * 8);
            floatx4 acc = {0.f, 0.f, 0.f, 0.f};
            acc = MFMA16(a0, wdh0, acc);
            acc = MFMA16(a1, wdh1, acc);
#pragma unroll
            for (int r = 0; r < 4; ++r) {
                float g = __expf(-fmaxf(acc[r] + bd, 0.0f));
                hreg[r] *= g;
                sh_hbf[(q * 4 + r) * 264 + colH] = __float2bfloat16(hreg[r]);
            }
        }
        __syncthreads();  // bar B

        // DMA slot 0 for P5 — flies behind P2/P34 compute
        stage_slot(Wp5, &sh_wbuf[0][0], 0, tid);

        // ---- P2: x_h (waves 0-3, register weights) ----
        float xh[4];
        float l1 = 0.f, l2 = 0.f, l3 = 0.f;
        if (wid < 4) {
            floatx4 acc = {0.f, 0.f, 0.f, 0.f};
#pragma unroll
            for (int kb = 0; kb < 8; ++kb) {
                short8 a = *(const short8*)(sh_hbf + l16 * 264 + kb * 32 + q * 8);
                acc = MFMA16(a, wh[kb], acc);
            }
#pragma unroll
            for (int r = 0; r < 4; ++r) {
                int row = q * 4 + r;
                xh[r] = acc[r] + bh;
                float xx = sh_x[row * 64 + colH], mm = sh_m[row * 64 + colH];
                l1 += fabsf(xh[r] - xx) * mm;
                float xc = mm * xx + (1.0f - mm) * xh[r];
                sh_xcbf[row * 72 + colH] = __float2bfloat16(xc);
            }
        }
        __syncthreads();  // bar C (drains slot-0 DMA too)

        // ---- P34: z_h, alpha, c_h, imputed write, c_c (waves 0-3) ----
        if (wid < 4) {
            floatx4 accz = {0.f, 0.f, 0.f, 0.f};
            {
                short8 a = *(const short8*)(sh_xcbf + l16 * 72 + q * 8);
                accz = MFMA16(a, wf0, accz);
                a = *(const short8*)(sh_xcbf + l16 * 72 + 32 + q * 8);
                accz = MFMA16(a, wf1, accz);
            }
            floatx4 acca = {0.f, 0.f, 0.f, 0.f};
            {
                short8 a = *(const short8*)(sh_gmbf + l16 * 136 + q * 8);
                acca = MFMA16(a, wc0, acca);
                a = *(const short8*)(sh_gmbf + l16 * 136 + 32 + q * 8);
                acca = MFMA16(a, wc1, acca);
                a = *(const short8*)(sh_gmbf + l16 * 136 + 64 + q * 8);
                acca = MFMA16(a, wc2, acca);
                a = *(const short8*)(sh_gmbf + l16 * 136 + 96 + q * 8);
                acca = MFMA16(a, wc3, acca);
            }
#pragma unroll
            for (int r = 0; r < 4; ++r) {
                int row = q * 4 + r;
                float xx = sh_x[row * 64 + colH], mm = sh_m[row * 64 + colH];
                float z = accz[r] + bft;
                l2 += fabsf(z - xx) * mm;
                float al = sigmf(acca[r] + bc);
                float ch = al * z + (1.0f - al) * xh[r];
                l3 += fabsf(ch - xx) * mm;
                float imp = mm * xx + (1.0f - mm) * ch;  // == c_c
                out[((size_t)(b0 + row) * Tz + t) * Fz + colH] = imp;
                sh_inbf[row * 136 + colH] = __float2bfloat16(imp);
            }
            float v1 = l1, v2 = l2, v3 = l3;
#pragma unroll
            for (int off = 32; off; off >>= 1) {
                v1 += __shfl_xor(v1, off, 64);
                v2 += __shfl_xor(v2, off, 64);
                v3 += __shfl_xor(v3, off, 64);
            }
            if (lane == 0) {
                sh_lred[wid * 4 + 0] = v1;
                sh_lred[wid * 4 + 1] = v2;
                sh_lred[wid * 4 + 2] = v3;
            }
        }
        __syncthreads();  // bar D

        if (tid == 0) {
            float s0 = 0.0f;
#pragma unroll
            for (int i = 0; i < 16; ++i) s0 += sh_msum[i];
            float* lb = lossbuf + ((size_t)blockIdx.x * Tz + t) * 4;
            lb[0] = s0;
            lb[1] = sh_lred[0] + sh_lred[4] + sh_lred[8] + sh_lred[12];
            lb[2] = sh_lred[1] + sh_lred[5] + sh_lred[9] + sh_lred[13];
            lb[3] = sh_lred[2] + sh_lred[6] + sh_lred[10] + sh_lred[14];
        }

        // input prefetch for t+1
        if (t + 1 < Tz) {
            size_t g = g0 + (size_t)(t + 1) * Fz;
            xv = X[g]; mv = Mm[g]; dv = Dd[g];
        }

        // ---- P5: gates GEMM; double-buffered DMA-staged weight stream.
        // iter s: issue DMA slot s+1 -> buf[(s+1)&1]; MFMA slot s from buf[s&1];
        // __syncthreads drains. slot0 pre-staged at P2. Final barrier doubles
        // as end-of-step barrier protecting sh_* for next iteration's P0.
        {
            floatx4 acc[4];
#pragma unroll
            for (int g = 0; g < 4; ++g) acc[g] = (floatx4){0.f, 0.f, 0.f, 0.f};
#pragma unroll
            for (int s = 0; s < 12; ++s) {
                if (s < 11) stage_slot(Wp5, &sh_wbuf[(s + 1) & 1][0], s + 1, tid);
                short8 a = (s < 4) ? *(const short8*)(sh_inbf + l16 * 136 + s * 32 + q * 8)
                                   : *(const short8*)(sh_hbf + l16 * 264 + (s - 4) * 32 + q * 8);
                const bf16* wb = &sh_wbuf[s & 1][wid * 2048 + l16 * 32 + q * 8];
#pragma unroll
                for (int g = 0; g < 4; ++g)
                    acc[g] = MFMA16(a, *(const short8*)(wb + g * 512), acc[g]);
                __syncthreads();
            }
#pragma unroll
            for (int r = 0; r < 4; ++r) {
                float ig = sigmf(acc[0][r] + bi);
                float fg = sigmf(acc[1][r] + bff);
                float gg = tanhfast(acc[2][r] + bgg);
                float og = sigmf(acc[3][r] + boo);
                creg[r] = fg * creg[r] + ig * gg;
                hreg[r] = og * tanhfast(creg[r]);
            }
        }
    }
}

__global__ void rits_finalize(const float* __restrict__ lossbuf, float* __restrict__ out) {
    __shared__ float m1[Tz], m2[Tz], m3[Tz];
    int t = threadIdx.x;
    if (t < Tz) {
        float s0 = 0.0f, s1 = 0.0f, s2 = 0.0f, s3 = 0.0f;
        for (int g = 0; g < GRID; ++g) {
            const float* lb = lossbuf + ((size_t)g * Tz + t) * 4;
            s0 += lb[0]; s1 += lb[1]; s2 += lb[2]; s3 += lb[3];
        }
        float inv = 1.0f / (s0 + 1e-9f);
        m1[t] = s1 * inv; m2[t] = s2 * inv; m3[t] = s3 * inv;
    }
    __syncthreads();
    if (t == 0) {
        float rm = 0.0f, rl = 0.0f;
        for (int i = 0; i < Tz; ++i) {  // literal replay of reference accumulation
            rl += m1[i]; rl += m2[i]; rm += m3[i]; rl += rm;
        }
        out[(size_t)Bz * Tz * Fz] = rm / (float)Tz;
        out[(size_t)Bz * Tz * Fz + 1] = rl / (3.0f * (float)Tz);
    }
}

extern "C" void kernel_launch(void* const* d_in, const int* in_sizes, int n_in,
                              void* d_out, int out_size, void* d_ws, size_t ws_size,
                              hipStream_t stream) {
    const float* X = (const float*)d_in[0];
    const float* Mm = (const float*)d_in[1];
    const float* Dd = (const float*)d_in[2];
    const float* Wdh = (const float*)d_in[3];
    const float* b_dh = (const float*)d_in[4];
    const float* Wdx = (const float*)d_in[5];
    const float* b_dx = (const float*)d_in[6];
    const float* Whist = (const float*)d_in[7];
    const float* b_hist = (const float*)d_in[8];
    const float* Wfeat = (const float*)d_in[9];
    const float* b_feat = (const float*)d_in[10];
    const float* Wcomb = (const float*)d_in[11];
    const float* b_comb = (const float*)d_in[12];
    const float* Wih = (const float*)d_in[13];
    const float* b_ih = (const float*)d_in[14];
    const float* Whh = (const float*)d_in[15];
    const float* b_hh = (const float*)d_in[16];
    float* out = (float*)d_out;

    bf16* wsbf = (bf16*)d_ws;
    float* wdxd = (float*)((char*)d_ws + (size_t)438272 * 2);
    float* lossbuf = wdxd + 64;

    rits_convert<<<1712, 256, 0, stream>>>(Wdh, Wdx, Whist, Wfeat, Wcomb, Wih, Whh, wsbf, wdxd);
    rits_main<<<GRID, 1024, 0, stream>>>(X, Mm, Dd, b_dh, b_dx, b_hist, b_feat, b_comb, b_ih, b_hh,
                                         wsbf + 0, wsbf + 16384, wsbf + 32768, wsbf + 36864,
                                         wsbf + 45056, wdxd, lossbuf, out);
    rits_finalize<<<1, 128, 0, stream>>>(lossbuf, out);
}